// Round 6
// baseline (122.737 us; speedup 1.0000x reference)
//
#include <hip/hip_runtime.h>
#include <hip/hip_bf16.h>

#define DD 128
#define DEG 32

typedef __attribute__((ext_vector_type(8))) short short8;
typedef __attribute__((ext_vector_type(8))) _Float16 half8;
typedef __attribute__((ext_vector_type(4))) float f32x4;

__device__ __forceinline__ ushort f2bs(float x) {
    __hip_bfloat16 h = __float2bfloat16(x);     // RNE
    return *reinterpret_cast<ushort*>(&h);
}
__device__ __forceinline__ unsigned pack2(float a, float b) {
    return (unsigned)f2bs(a) | ((unsigned)f2bs(b) << 16);
}
// relu(bf16(p_lo)+bf16(q_lo)), relu(bf16(p_hi)+bf16(q_hi)) -> packed bf16 pair
__device__ __forceinline__ unsigned relu_add_pack(unsigned p, unsigned q) {
    float a0 = __uint_as_float(p << 16)        + __uint_as_float(q << 16);
    float a1 = __uint_as_float(p & 0xffff0000u) + __uint_as_float(q & 0xffff0000u);
    return pack2(fmaxf(a0, 0.f), fmaxf(a1, 0.f));
}

// ---------------------------------------------------------------------------
// k_prep: build MFMA fragment images in ws (read straight from global later).
//  w1img (64KB): frag(nt,k4,l)[i] = B1[k4*32+(l>>4)*8+i][nt*16+(l&15)]
//     where B1[k][n] = W1[k][n] (n<128)  |  W1[128+k][n-128] (n>=128)
//  w2t   (32KB): frag(mt,k4,l)[i] = W2[k4*32+(l>>4)*8+i][mt*16+(l&15)]
// ---------------------------------------------------------------------------
__global__ __launch_bounds__(256) void k_prep(
    const float* __restrict__ W1, const float* __restrict__ W2,
    uint4* __restrict__ w1img, uint4* __restrict__ w2t)
{
    int t = blockIdx.x * 256 + threadIdx.x;
    if (t < 4096) {                     // w1: idx = (nt*4+k4)*64 + l
        int l = t & 63, f = t >> 6, k4 = f & 3, nt = f >> 2;
        int n = nt * 16 + (l & 15), kb = k4 * 32 + ((l >> 4) & 3) * 8;
        float v[8];
        #pragma unroll
        for (int i = 0; i < 8; ++i) {
            int k = kb + i;
            v[i] = (n < DD) ? W1[k * DD + n] : W1[(DD + k) * DD + (n - DD)];
        }
        uint4 r;
        r.x = pack2(v[0], v[1]); r.y = pack2(v[2], v[3]);
        r.z = pack2(v[4], v[5]); r.w = pack2(v[6], v[7]);
        w1img[t] = r;
    } else if (t < 6144) {              // w2t: idx = (mt*4+k4)*64 + l
        int q = t - 4096;
        int l = q & 63, f = q >> 6, k4 = f & 3, mt = f >> 2;
        int ch = mt * 16 + (l & 15), kb = k4 * 32 + ((l >> 4) & 3) * 8;
        float v[8];
        #pragma unroll
        for (int i = 0; i < 8; ++i) v[i] = W2[(kb + i) * DD + ch];
        uint4 r;
        r.x = pack2(v[0], v[1]); r.y = pack2(v[2], v[3]);
        r.z = pack2(v[4], v[5]); r.w = pack2(v[6], v[7]);
        w2t[q] = r;
    }
}

// ---------------------------------------------------------------------------
// k_pq: [P|Q](u) = u2e[u] @ [W1a|W1b] (+b1 on Q), bf16 out; also e16=fp16(u2e).
// 128 users/block, NO LDS, NO barriers: A-fragments loaded directly from
// u2e with per-lane addresses; e16 written from the same registers.
// Swapped epilogue: D=mfma(W1frag, u2efrag) -> row=ch, col=user.
// ---------------------------------------------------------------------------
__global__ __launch_bounds__(256) void k_pq(
    const float* __restrict__ u2e, const float* __restrict__ b1,
    const short8* __restrict__ w1img, ushort* __restrict__ Pb,
    ushort* __restrict__ Qb, _Float16* __restrict__ e16, int U)
{
    const int t = threadIdx.x;
    const int w = t >> 6, l = t & 63;
    const int base = blockIdx.x * 128;

    // ---- direct A-fragments (role: MFMA B operand; row=user) + e16 emit
    short8 a[2][4];
    #pragma unroll
    for (int mt = 0; mt < 2; ++mt) {
        int user = base + w * 32 + mt * 16 + (l & 15);
        int ruser = min(user, U - 1);
        const float* rp = u2e + (size_t)ruser * DD + ((l >> 4) << 3);
        #pragma unroll
        for (int k4 = 0; k4 < 4; ++k4) {
            float4 v0 = *reinterpret_cast<const float4*>(rp + k4 * 32);
            float4 v1 = *reinterpret_cast<const float4*>(rp + k4 * 32 + 4);
            uint4 r;
            r.x = pack2(v0.x, v0.y); r.y = pack2(v0.z, v0.w);
            r.z = pack2(v1.x, v1.y); r.w = pack2(v1.z, v1.w);
            a[mt][k4] = *reinterpret_cast<short8*>(&r);
            if (user < U) {
                half8 hv;
                hv[0] = (_Float16)v0.x; hv[1] = (_Float16)v0.y;
                hv[2] = (_Float16)v0.z; hv[3] = (_Float16)v0.w;
                hv[4] = (_Float16)v1.x; hv[5] = (_Float16)v1.y;
                hv[6] = (_Float16)v1.z; hv[7] = (_Float16)v1.w;
                *reinterpret_cast<half8*>(
                    &e16[(size_t)user * DD + k4 * 32 + ((l >> 4) << 3)]) = hv;
            }
        }
    }

    const int chq = (l >> 4) << 2;            // lane's 4-channel sub-block
    // ---- P half: output channels 0..127
    #pragma unroll 2
    for (int mt = 0; mt < 8; ++mt) {
        short8 wf[4];
        #pragma unroll
        for (int k4 = 0; k4 < 4; ++k4) wf[k4] = w1img[(mt * 4 + k4) * 64 + l];
        #pragma unroll
        for (int ntu = 0; ntu < 2; ++ntu) {
            f32x4 acc = {0.f, 0.f, 0.f, 0.f};
            #pragma unroll
            for (int k4 = 0; k4 < 4; ++k4)
                acc = __builtin_amdgcn_mfma_f32_16x16x32_bf16(wf[k4], a[ntu][k4], acc, 0, 0, 0);
            int user = base + w * 32 + ntu * 16 + (l & 15);
            if (user < U) {
                uint2 pk;
                pk.x = pack2(acc[0], acc[1]); pk.y = pack2(acc[2], acc[3]);
                *reinterpret_cast<uint2*>(&Pb[(size_t)user * DD + mt * 16 + chq]) = pk;
            }
        }
    }
    // ---- Q half: output channels 128..255, fold b1
    #pragma unroll 2
    for (int mt = 8; mt < 16; ++mt) {
        short8 wf[4];
        #pragma unroll
        for (int k4 = 0; k4 < 4; ++k4) wf[k4] = w1img[(mt * 4 + k4) * 64 + l];
        float4 b1v = *reinterpret_cast<const float4*>(&b1[(mt - 8) * 16 + chq]);
        #pragma unroll
        for (int ntu = 0; ntu < 2; ++ntu) {
            f32x4 acc = {0.f, 0.f, 0.f, 0.f};
            #pragma unroll
            for (int k4 = 0; k4 < 4; ++k4)
                acc = __builtin_amdgcn_mfma_f32_16x16x32_bf16(wf[k4], a[ntu][k4], acc, 0, 0, 0);
            int user = base + w * 32 + ntu * 16 + (l & 15);
            if (user < U) {
                uint2 pk;
                pk.x = pack2(acc[0] + b1v.x, acc[1] + b1v.y);
                pk.y = pack2(acc[2] + b1v.z, acc[3] + b1v.w);
                *reinterpret_cast<uint2*>(&Qb[(size_t)user * DD + (mt - 8) * 16 + chq]) = pk;
            }
        }
    }
}

// ---------------------------------------------------------------------------
// k_node: 4 nodes/block, 1 node per wave, NO pre-GEMM barriers, no h1 LDS.
//  h1 MFMA fragments are built in registers from direct global gathers:
//  hb[nt][k4] = relu_pack(Pb[nb][chunk] + Qb[u][chunk]).
//  Swapped GEMM D[ch][edge]; in-lane logit + 2 shuffles; in-wave softmax;
//  fp32 weighted sum of prefetched fp16 e16 rows.
// ---------------------------------------------------------------------------
__global__ __launch_bounds__(256) void k_node(
    const int* __restrict__ nodes, const int* __restrict__ neigh,
    const _Float16* __restrict__ e16, const ushort* __restrict__ Pb,
    const ushort* __restrict__ Qb, const short8* __restrict__ w2t,
    const float* __restrict__ b2, const float* __restrict__ w3,
    float4* __restrict__ out4, int n)
{
    __shared__ float s_att[128];
    __shared__ float s_part[16 * 128];    // 8 KB: [jg(4)][node(4)][128ch]

    const int t = threadIdx.x;
    const int w = t >> 6, l = t & 63;
    const int base = blockIdx.x * 4;
    const int node = base + w;

    // ---- prefetch e16 rows for the weighted sum (deep, no barrier ahead)
    // thread (w=jg, g4, c8): 8 edges of node base+g4, channel chunk c8.
    const int g4 = (t >> 4) & 3, c8 = t & 15;
    half8 pre[8];
    #pragma unroll
    for (int j = 0; j < 8; ++j) {
        int nb = neigh[(base + g4) * DEG + w * 8 + j];
        pre[j] = *reinterpret_cast<const half8*>(&e16[(size_t)nb * DD + c8 * 8]);
    }

    // ---- h1 fragments straight from global (gathered per-lane)
    const int u = nodes[node];
    const int koff = ((l >> 4) << 3);         // k-chunk base within k4 section
    uint4 qv[4];
    #pragma unroll
    for (int k4 = 0; k4 < 4; ++k4)
        qv[k4] = *reinterpret_cast<const uint4*>(&Qb[(size_t)u * DD + k4 * 32 + koff]);
    short8 hb[2][4];
    #pragma unroll
    for (int nt = 0; nt < 2; ++nt) {
        int nb = neigh[node * DEG + nt * 16 + (l & 15)];
        const ushort* prow = Pb + (size_t)nb * DD + koff;
        #pragma unroll
        for (int k4 = 0; k4 < 4; ++k4) {
            uint4 pv = *reinterpret_cast<const uint4*>(prow + k4 * 32);
            uint4 r;
            r.x = relu_add_pack(pv.x, qv[k4].x);
            r.y = relu_add_pack(pv.y, qv[k4].y);
            r.z = relu_add_pack(pv.z, qv[k4].z);
            r.w = relu_add_pack(pv.w, qv[k4].w);
            hb[nt][k4] = *reinterpret_cast<short8*>(&r);
        }
    }

    // ---- swapped GEMM + logit fold (wave w = node w, 32 edges)
    float pl0 = 0.f, pl1 = 0.f;
    #pragma unroll
    for (int mt = 0; mt < 8; ++mt) {
        short8 wf[4];
        #pragma unroll
        for (int k4 = 0; k4 < 4; ++k4) wf[k4] = w2t[(mt * 4 + k4) * 64 + l];
        float4 b2v = *reinterpret_cast<const float4*>(&b2[mt * 16 + (l >> 4) * 4]);
        float4 w3v = *reinterpret_cast<const float4*>(&w3[mt * 16 + (l >> 4) * 4]);
        f32x4 a0 = {0.f, 0.f, 0.f, 0.f}, a1 = {0.f, 0.f, 0.f, 0.f};
        #pragma unroll
        for (int k4 = 0; k4 < 4; ++k4)
            a0 = __builtin_amdgcn_mfma_f32_16x16x32_bf16(wf[k4], hb[0][k4], a0, 0, 0, 0);
        #pragma unroll
        for (int k4 = 0; k4 < 4; ++k4)
            a1 = __builtin_amdgcn_mfma_f32_16x16x32_bf16(wf[k4], hb[1][k4], a1, 0, 0, 0);
        pl0 += fmaxf(a0[0] + b2v.x, 0.f) * w3v.x + fmaxf(a0[1] + b2v.y, 0.f) * w3v.y
             + fmaxf(a0[2] + b2v.z, 0.f) * w3v.z + fmaxf(a0[3] + b2v.w, 0.f) * w3v.w;
        pl1 += fmaxf(a1[0] + b2v.x, 0.f) * w3v.x + fmaxf(a1[1] + b2v.y, 0.f) * w3v.y
             + fmaxf(a1[2] + b2v.z, 0.f) * w3v.z + fmaxf(a1[3] + b2v.w, 0.f) * w3v.w;
    }
    pl0 += __shfl_xor(pl0, 16); pl0 += __shfl_xor(pl0, 32);
    pl1 += __shfl_xor(pl1, 16); pl1 += __shfl_xor(pl1, 32);

    // ---- in-wave softmax over this wave's node (32 edges)
    float mx = fmaxf(pl0, pl1);
    #pragma unroll
    for (int mask = 1; mask <= 8; mask <<= 1) mx = fmaxf(mx, __shfl_xor(mx, mask));
    float e0 = __expf(pl0 - mx), e1 = __expf(pl1 - mx);
    float sm = e0 + e1;
    #pragma unroll
    for (int mask = 1; mask <= 8; mask <<= 1) sm += __shfl_xor(sm, mask);
    if (l < 16) {
        float inv = __frcp_rn(sm);
        s_att[w * DEG + l]      = e0 * inv;
        s_att[w * DEG + 16 + l] = e1 * inv;
    }
    __syncthreads();

    // ---- attention-weighted sum from fp16 prefetch (exact fp32 accum)
    float4 oa = make_float4(0.f, 0.f, 0.f, 0.f), ob = oa;
    #pragma unroll
    for (int j = 0; j < 8; ++j) {
        float a = s_att[g4 * DEG + w * 8 + j];
        oa.x = fmaf(a, (float)pre[j][0], oa.x); oa.y = fmaf(a, (float)pre[j][1], oa.y);
        oa.z = fmaf(a, (float)pre[j][2], oa.z); oa.w = fmaf(a, (float)pre[j][3], oa.w);
        ob.x = fmaf(a, (float)pre[j][4], ob.x); ob.y = fmaf(a, (float)pre[j][5], ob.y);
        ob.z = fmaf(a, (float)pre[j][6], ob.z); ob.w = fmaf(a, (float)pre[j][7], ob.w);
    }
    {
        float4* sp = reinterpret_cast<float4*>(s_part + ((w * 4 + g4) * 128 + c8 * 8));
        sp[0] = oa; sp[1] = ob;
    }
    __syncthreads();
    if (t < 128) {
        int g = t >> 5, c4 = t & 31;
        float4 r = make_float4(0.f, 0.f, 0.f, 0.f);
        #pragma unroll
        for (int j2 = 0; j2 < 4; ++j2) {
            const float* sp = s_part + ((j2 * 4 + g) * 128 + c4 * 4);
            r.x += sp[0]; r.y += sp[1]; r.z += sp[2]; r.w += sp[3];
        }
        if (base + g < n) out4[(size_t)(base + g) * 32 + c4] = r;
    }
}

// ---------------------------------------------------------------------------
extern "C" void kernel_launch(void* const* d_in, const int* in_sizes, int n_in,
                              void* d_out, int out_size, void* d_ws, size_t ws_size,
                              hipStream_t stream)
{
    const int*   nodes = (const int*)  d_in[0];
    const int*   neigh = (const int*)  d_in[1];
    const float* u2e   = (const float*)d_in[3];
    const float* W1    = (const float*)d_in[4];
    const float* b1    = (const float*)d_in[5];
    const float* W2    = (const float*)d_in[6];
    const float* b2    = (const float*)d_in[7];
    const float* w3    = (const float*)d_in[8];
    // d_in[9] b3: cancels in segment softmax

    const int n = in_sizes[0];            // 20000
    const int U = in_sizes[3] / DD;       // 100000

    uint4*     w1img = (uint4*)d_ws;                  // 64 KB (4096 uint4)
    uint4*     w2t   = w1img + 4096;                  // 32 KB (2048 uint4)
    ushort*    Pb    = (ushort*)(w2t + 2048);         // 25.6 MB
    ushort*    Qb    = Pb + (size_t)U * DD;           // 25.6 MB
    _Float16*  e16   = (_Float16*)(Qb + (size_t)U * DD); // 25.6 MB

    k_prep<<<24, 256, 0, stream>>>(W1, W2, w1img, w2t);
    k_pq<<<(U + 127) / 128, 256, 0, stream>>>(u2e, b1, (const short8*)w1img,
                                              Pb, Qb, e16, U);
    k_node<<<(n + 3) / 4, 256, 0, stream>>>(nodes, neigh, e16,
                                            Pb, Qb,
                                            (const short8*)w2t, b2, w3,
                                            (float4*)d_out, n);
}

// Round 7
// 110.070 us; speedup vs baseline: 1.1151x; 1.1151x over previous
//
#include <hip/hip_runtime.h>
#include <hip/hip_bf16.h>

#define DD 128
#define DEG 32

typedef __attribute__((ext_vector_type(8))) short short8;
typedef __attribute__((ext_vector_type(8))) _Float16 half8;
typedef __attribute__((ext_vector_type(4))) float f32x4;

__device__ __forceinline__ ushort f2bs(float x) {
    __hip_bfloat16 h = __float2bfloat16(x);     // RNE
    return *reinterpret_cast<ushort*>(&h);
}
__device__ __forceinline__ unsigned pack2(float a, float b) {
    return (unsigned)f2bs(a) | ((unsigned)f2bs(b) << 16);
}
// relu(bf16(p_lo)+bf16(q_lo)), relu(bf16(p_hi)+bf16(q_hi)) -> packed bf16 pair
__device__ __forceinline__ unsigned relu_add_pack(unsigned p, unsigned q) {
    float a0 = __uint_as_float(p << 16)        + __uint_as_float(q << 16);
    float a1 = __uint_as_float(p & 0xffff0000u) + __uint_as_float(q & 0xffff0000u);
    return pack2(fmaxf(a0, 0.f), fmaxf(a1, 0.f));
}

// ---------------------------------------------------------------------------
// k_prep: build MFMA fragment images in ws (read straight from global later).
//  w1img (64KB): frag(nt,k4,l)[i] = B1[k4*32+(l>>4)*8+i][nt*16+(l&15)]
//     where B1[k][n] = W1[k][n] (n<128)  |  W1[128+k][n-128] (n>=128)
//  w2t   (32KB): frag(mt,k4,l)[i] = W2[k4*32+(l>>4)*8+i][mt*16+(l&15)]
// ---------------------------------------------------------------------------
__global__ __launch_bounds__(256) void k_prep(
    const float* __restrict__ W1, const float* __restrict__ W2,
    uint4* __restrict__ w1img, uint4* __restrict__ w2t)
{
    int t = blockIdx.x * 256 + threadIdx.x;
    if (t < 4096) {                     // w1: idx = (nt*4+k4)*64 + l
        int l = t & 63, f = t >> 6, k4 = f & 3, nt = f >> 2;
        int n = nt * 16 + (l & 15), kb = k4 * 32 + ((l >> 4) & 3) * 8;
        float v[8];
        #pragma unroll
        for (int i = 0; i < 8; ++i) {
            int k = kb + i;
            v[i] = (n < DD) ? W1[k * DD + n] : W1[(DD + k) * DD + (n - DD)];
        }
        uint4 r;
        r.x = pack2(v[0], v[1]); r.y = pack2(v[2], v[3]);
        r.z = pack2(v[4], v[5]); r.w = pack2(v[6], v[7]);
        w1img[t] = r;
    } else if (t < 6144) {              // w2t: idx = (mt*4+k4)*64 + l
        int q = t - 4096;
        int l = q & 63, f = q >> 6, k4 = f & 3, mt = f >> 2;
        int ch = mt * 16 + (l & 15), kb = k4 * 32 + ((l >> 4) & 3) * 8;
        float v[8];
        #pragma unroll
        for (int i = 0; i < 8; ++i) v[i] = W2[(kb + i) * DD + ch];
        uint4 r;
        r.x = pack2(v[0], v[1]); r.y = pack2(v[2], v[3]);
        r.z = pack2(v[4], v[5]); r.w = pack2(v[6], v[7]);
        w2t[q] = r;
    }
}

// ---------------------------------------------------------------------------
// k_pq: [P|Q](u) = u2e[u] @ [W1a|W1b] (+b1 on Q), bf16 out; also e16=fp16(u2e).
// 128 users/block, NO LDS, NO barriers: A-fragments loaded directly from
// u2e with per-lane addresses; e16 written from the same registers.
// Swapped epilogue: D=mfma(W1frag, u2efrag) -> row=ch, col=user.
// ---------------------------------------------------------------------------
__global__ __launch_bounds__(256) void k_pq(
    const float* __restrict__ u2e, const float* __restrict__ b1,
    const short8* __restrict__ w1img, ushort* __restrict__ Pb,
    ushort* __restrict__ Qb, _Float16* __restrict__ e16, int U)
{
    const int t = threadIdx.x;
    const int w = t >> 6, l = t & 63;
    const int base = blockIdx.x * 128;

    // ---- direct A-fragments (role: MFMA B operand; row=user) + e16 emit
    short8 a[2][4];
    #pragma unroll
    for (int mt = 0; mt < 2; ++mt) {
        int user = base + w * 32 + mt * 16 + (l & 15);
        int ruser = min(user, U - 1);
        const float* rp = u2e + (size_t)ruser * DD + ((l >> 4) << 3);
        #pragma unroll
        for (int k4 = 0; k4 < 4; ++k4) {
            float4 v0 = *reinterpret_cast<const float4*>(rp + k4 * 32);
            float4 v1 = *reinterpret_cast<const float4*>(rp + k4 * 32 + 4);
            uint4 r;
            r.x = pack2(v0.x, v0.y); r.y = pack2(v0.z, v0.w);
            r.z = pack2(v1.x, v1.y); r.w = pack2(v1.z, v1.w);
            a[mt][k4] = *reinterpret_cast<short8*>(&r);
            if (user < U) {
                half8 hv;
                hv[0] = (_Float16)v0.x; hv[1] = (_Float16)v0.y;
                hv[2] = (_Float16)v0.z; hv[3] = (_Float16)v0.w;
                hv[4] = (_Float16)v1.x; hv[5] = (_Float16)v1.y;
                hv[6] = (_Float16)v1.z; hv[7] = (_Float16)v1.w;
                *reinterpret_cast<half8*>(
                    &e16[(size_t)user * DD + k4 * 32 + ((l >> 4) << 3)]) = hv;
            }
        }
    }

    const int chq = (l >> 4) << 2;            // lane's 4-channel sub-block
    // ---- P half: output channels 0..127
    #pragma unroll 2
    for (int mt = 0; mt < 8; ++mt) {
        short8 wf[4];
        #pragma unroll
        for (int k4 = 0; k4 < 4; ++k4) wf[k4] = w1img[(mt * 4 + k4) * 64 + l];
        #pragma unroll
        for (int ntu = 0; ntu < 2; ++ntu) {
            f32x4 acc = {0.f, 0.f, 0.f, 0.f};
            #pragma unroll
            for (int k4 = 0; k4 < 4; ++k4)
                acc = __builtin_amdgcn_mfma_f32_16x16x32_bf16(wf[k4], a[ntu][k4], acc, 0, 0, 0);
            int user = base + w * 32 + ntu * 16 + (l & 15);
            if (user < U) {
                uint2 pk;
                pk.x = pack2(acc[0], acc[1]); pk.y = pack2(acc[2], acc[3]);
                *reinterpret_cast<uint2*>(&Pb[(size_t)user * DD + mt * 16 + chq]) = pk;
            }
        }
    }
    // ---- Q half: output channels 128..255, fold b1
    #pragma unroll 2
    for (int mt = 8; mt < 16; ++mt) {
        short8 wf[4];
        #pragma unroll
        for (int k4 = 0; k4 < 4; ++k4) wf[k4] = w1img[(mt * 4 + k4) * 64 + l];
        float4 b1v = *reinterpret_cast<const float4*>(&b1[(mt - 8) * 16 + chq]);
        #pragma unroll
        for (int ntu = 0; ntu < 2; ++ntu) {
            f32x4 acc = {0.f, 0.f, 0.f, 0.f};
            #pragma unroll
            for (int k4 = 0; k4 < 4; ++k4)
                acc = __builtin_amdgcn_mfma_f32_16x16x32_bf16(wf[k4], a[ntu][k4], acc, 0, 0, 0);
            int user = base + w * 32 + ntu * 16 + (l & 15);
            if (user < U) {
                uint2 pk;
                pk.x = pack2(acc[0] + b1v.x, acc[1] + b1v.y);
                pk.y = pack2(acc[2] + b1v.z, acc[3] + b1v.w);
                *reinterpret_cast<uint2*>(&Qb[(size_t)user * DD + (mt - 8) * 16 + chq]) = pk;
            }
        }
    }
}

// ---------------------------------------------------------------------------
// k_node: fully wave-independent — 1 node per wave, ZERO LDS, ZERO barriers.
//  h1 fragments from direct global gathers (pv0/pv1 issued back-to-back);
//  swapped GEMM D[ch][edge]; logit reduce = 2 shuffles; in-wave softmax;
//  att distributed via __shfl; e16 gather + fp32 weighted sum reduced via
//  __shfl_xor(16/32); lanes 0..15 store the 512B output row.
// ---------------------------------------------------------------------------
__global__ __launch_bounds__(256) void k_node(
    const int* __restrict__ nodes, const int* __restrict__ neigh,
    const _Float16* __restrict__ e16, const ushort* __restrict__ Pb,
    const ushort* __restrict__ Qb, const short8* __restrict__ w2t,
    const float* __restrict__ b2, const float* __restrict__ w3,
    float4* __restrict__ out4, int n)
{
    const int t = threadIdx.x;
    const int w = t >> 6, l = t & 63;
    const int node = blockIdx.x * 4 + w;
    if (node >= n) return;

    const int lane16 = l & 15;
    const int koff = (l >> 4) << 3;           // k-chunk base within k4 section
    const int jg = l >> 4;                    // edge group for the tail

    // ---- index loads first (64B row, L1-resident for the tail reloads)
    const int u    = nodes[node];
    const int idx0 = neigh[node * DEG + lane16];
    const int idx1 = neigh[node * DEG + 16 + lane16];

    // ---- gathers: Qb (uniform row) + both Pb edge-tiles, all in flight
    uint4 qv[4];
    #pragma unroll
    for (int k4 = 0; k4 < 4; ++k4)
        qv[k4] = *reinterpret_cast<const uint4*>(&Qb[(size_t)u * DD + k4 * 32 + koff]);
    uint4 pv0[4], pv1[4];
    #pragma unroll
    for (int k4 = 0; k4 < 4; ++k4)
        pv0[k4] = *reinterpret_cast<const uint4*>(&Pb[(size_t)idx0 * DD + k4 * 32 + koff]);
    #pragma unroll
    for (int k4 = 0; k4 < 4; ++k4)
        pv1[k4] = *reinterpret_cast<const uint4*>(&Pb[(size_t)idx1 * DD + k4 * 32 + koff]);

    // ---- h1 fragments in registers
    short8 hb0[4], hb1[4];
    #pragma unroll
    for (int k4 = 0; k4 < 4; ++k4) {
        uint4 r;
        r.x = relu_add_pack(pv0[k4].x, qv[k4].x);
        r.y = relu_add_pack(pv0[k4].y, qv[k4].y);
        r.z = relu_add_pack(pv0[k4].z, qv[k4].z);
        r.w = relu_add_pack(pv0[k4].w, qv[k4].w);
        hb0[k4] = *reinterpret_cast<short8*>(&r);
        uint4 s;
        s.x = relu_add_pack(pv1[k4].x, qv[k4].x);
        s.y = relu_add_pack(pv1[k4].y, qv[k4].y);
        s.z = relu_add_pack(pv1[k4].z, qv[k4].z);
        s.w = relu_add_pack(pv1[k4].w, qv[k4].w);
        hb1[k4] = *reinterpret_cast<short8*>(&s);
    }

    // ---- swapped GEMM + logit fold (D col = edge, row = channel)
    float pl0 = 0.f, pl1 = 0.f;
    #pragma unroll
    for (int mt = 0; mt < 8; ++mt) {
        short8 wf[4];
        #pragma unroll
        for (int k4 = 0; k4 < 4; ++k4) wf[k4] = w2t[(mt * 4 + k4) * 64 + l];
        float4 b2v = *reinterpret_cast<const float4*>(&b2[mt * 16 + (l >> 4) * 4]);
        float4 w3v = *reinterpret_cast<const float4*>(&w3[mt * 16 + (l >> 4) * 4]);
        f32x4 a0 = {0.f, 0.f, 0.f, 0.f}, a1 = {0.f, 0.f, 0.f, 0.f};
        #pragma unroll
        for (int k4 = 0; k4 < 4; ++k4)
            a0 = __builtin_amdgcn_mfma_f32_16x16x32_bf16(wf[k4], hb0[k4], a0, 0, 0, 0);
        #pragma unroll
        for (int k4 = 0; k4 < 4; ++k4)
            a1 = __builtin_amdgcn_mfma_f32_16x16x32_bf16(wf[k4], hb1[k4], a1, 0, 0, 0);
        pl0 += fmaxf(a0[0] + b2v.x, 0.f) * w3v.x + fmaxf(a0[1] + b2v.y, 0.f) * w3v.y
             + fmaxf(a0[2] + b2v.z, 0.f) * w3v.z + fmaxf(a0[3] + b2v.w, 0.f) * w3v.w;
        pl1 += fmaxf(a1[0] + b2v.x, 0.f) * w3v.x + fmaxf(a1[1] + b2v.y, 0.f) * w3v.y
             + fmaxf(a1[2] + b2v.z, 0.f) * w3v.z + fmaxf(a1[3] + b2v.w, 0.f) * w3v.w;
    }
    pl0 += __shfl_xor(pl0, 16); pl0 += __shfl_xor(pl0, 32);
    pl1 += __shfl_xor(pl1, 16); pl1 += __shfl_xor(pl1, 32);
    // now every lane: pl0 = logit(edge lane16), pl1 = logit(edge 16+lane16)

    // ---- in-wave softmax over 32 edges
    float mx = fmaxf(pl0, pl1);
    #pragma unroll
    for (int mask = 1; mask <= 8; mask <<= 1) mx = fmaxf(mx, __shfl_xor(mx, mask));
    float e0 = __expf(pl0 - mx), e1 = __expf(pl1 - mx);
    float sm = e0 + e1;
    #pragma unroll
    for (int mask = 1; mask <= 8; mask <<= 1) sm += __shfl_xor(sm, mask);
    float inv = __frcp_rn(sm);
    float att0 = e0 * inv, att1 = e1 * inv;

    // ---- e16 gather for the weighted sum: lane = (edge-group jg, chunk lane16)
    int   nbj[8];
    half8 pre[8];
    #pragma unroll
    for (int j = 0; j < 8; ++j)
        nbj[j] = neigh[node * DEG + jg * 8 + j];       // L1-hot line
    #pragma unroll
    for (int j = 0; j < 8; ++j)
        pre[j] = *reinterpret_cast<const half8*>(&e16[(size_t)nbj[j] * DD + lane16 * 8]);

    float o[8] = {0.f, 0.f, 0.f, 0.f, 0.f, 0.f, 0.f, 0.f};
    #pragma unroll
    for (int j = 0; j < 8; ++j) {
        int e = jg * 8 + j;
        float alo = __shfl(att0, e & 15);
        float ahi = __shfl(att1, e & 15);
        float a = (jg < 2) ? alo : ahi;
        #pragma unroll
        for (int i = 0; i < 8; ++i) o[i] = fmaf(a, (float)pre[j][i], o[i]);
    }
    // reduce over the 4 edge-groups (lanes sharing lane16)
    #pragma unroll
    for (int i = 0; i < 8; ++i) {
        o[i] += __shfl_xor(o[i], 16);
        o[i] += __shfl_xor(o[i], 32);
    }
    if (l < 16) {
        float4 r0 = make_float4(o[0], o[1], o[2], o[3]);
        float4 r1 = make_float4(o[4], o[5], o[6], o[7]);
        out4[(size_t)node * 32 + lane16 * 2]     = r0;
        out4[(size_t)node * 32 + lane16 * 2 + 1] = r1;
    }
}

// ---------------------------------------------------------------------------
extern "C" void kernel_launch(void* const* d_in, const int* in_sizes, int n_in,
                              void* d_out, int out_size, void* d_ws, size_t ws_size,
                              hipStream_t stream)
{
    const int*   nodes = (const int*)  d_in[0];
    const int*   neigh = (const int*)  d_in[1];
    const float* u2e   = (const float*)d_in[3];
    const float* W1    = (const float*)d_in[4];
    const float* b1    = (const float*)d_in[5];
    const float* W2    = (const float*)d_in[6];
    const float* b2    = (const float*)d_in[7];
    const float* w3    = (const float*)d_in[8];
    // d_in[9] b3: cancels in segment softmax

    const int n = in_sizes[0];            // 20000
    const int U = in_sizes[3] / DD;       // 100000

    uint4*     w1img = (uint4*)d_ws;                  // 64 KB (4096 uint4)
    uint4*     w2t   = w1img + 4096;                  // 32 KB (2048 uint4)
    ushort*    Pb    = (ushort*)(w2t + 2048);         // 25.6 MB
    ushort*    Qb    = Pb + (size_t)U * DD;           // 25.6 MB
    _Float16*  e16   = (_Float16*)(Qb + (size_t)U * DD); // 25.6 MB

    k_prep<<<24, 256, 0, stream>>>(W1, W2, w1img, w2t);
    k_pq<<<(U + 127) / 128, 256, 0, stream>>>(u2e, b1, (const short8*)w1img,
                                              Pb, Qb, e16, U);
    k_node<<<(n + 3) / 4, 256, 0, stream>>>(nodes, neigh, e16,
                                            Pb, Qb,
                                            (const short8*)w2t, b2, w3,
                                            (float4*)d_out, n);
}

// Round 8
// 108.299 us; speedup vs baseline: 1.1333x; 1.0163x over previous
//
#include <hip/hip_runtime.h>
#include <hip/hip_bf16.h>

#define DD 128
#define DEG 32

typedef __attribute__((ext_vector_type(8))) _Float16 half8;
typedef __attribute__((ext_vector_type(4))) float f32x4;

__device__ __forceinline__ unsigned pkh(float a, float b) {
    _Float16 ha = (_Float16)a, hb = (_Float16)b;     // RNE v_cvt_f16_f32
    return (unsigned)__builtin_bit_cast(unsigned short, ha)
         | ((unsigned)__builtin_bit_cast(unsigned short, hb) << 16);
}
__device__ __forceinline__ float h2f_lo(unsigned u) {
    return (float)__builtin_bit_cast(_Float16, (unsigned short)(u & 0xffff));
}
__device__ __forceinline__ float h2f_hi(unsigned u) {
    return (float)__builtin_bit_cast(_Float16, (unsigned short)(u >> 16));
}

// ---------------------------------------------------------------------------
// k_prep: fp16 MFMA fragment images (identical geometry to verified rounds):
//  w1img[(nt*4+k4)*64+l][i] = B1[k4*32+(l>>4)*8+i][nt*16+(l&15)]
//     B1[k][n] = W1[k][n] (n<128 -> "W1a") | W1[128+k][n-128] (n>=128 -> "W1b")
//  w2t  [(mt*4+k4)*64+l][i] = W2[k4*32+(l>>4)*8+i][mt*16+(l&15)]
// ---------------------------------------------------------------------------
__global__ __launch_bounds__(256) void k_prep(
    const float* __restrict__ W1, const float* __restrict__ W2,
    uint4* __restrict__ w1img, uint4* __restrict__ w2t)
{
    int t = blockIdx.x * 256 + threadIdx.x;
    if (t < 4096) {
        int l = t & 63, f = t >> 6, k4 = f & 3, nt = f >> 2;
        int n = nt * 16 + (l & 15), kb = k4 * 32 + ((l >> 4) & 3) * 8;
        float v[8];
        #pragma unroll
        for (int i = 0; i < 8; ++i) {
            int k = kb + i;
            v[i] = (n < DD) ? W1[k * DD + n] : W1[(DD + k) * DD + (n - DD)];
        }
        uint4 r;
        r.x = pkh(v[0], v[1]); r.y = pkh(v[2], v[3]);
        r.z = pkh(v[4], v[5]); r.w = pkh(v[6], v[7]);
        w1img[t] = r;
    } else if (t < 6144) {
        int q = t - 4096;
        int l = q & 63, f = q >> 6, k4 = f & 3, mt = f >> 2;
        int ch = mt * 16 + (l & 15), kb = k4 * 32 + ((l >> 4) & 3) * 8;
        float v[8];
        #pragma unroll
        for (int i = 0; i < 8; ++i) v[i] = W2[(kb + i) * DD + ch];
        uint4 r;
        r.x = pkh(v[0], v[1]); r.y = pkh(v[2], v[3]);
        r.z = pkh(v[4], v[5]); r.w = pkh(v[6], v[7]);
        w2t[q] = r;
    }
}

// ---------------------------------------------------------------------------
// k_cast: ub16 = fp16(u2e), streaming.
// ---------------------------------------------------------------------------
__global__ __launch_bounds__(256) void k_cast(
    const float4* __restrict__ u2e4, uint4* __restrict__ ub16v, int total8)
{
    int i = blockIdx.x * 256 + threadIdx.x;
    if (i >= total8) return;
    float4 v0 = u2e4[(size_t)i * 2], v1 = u2e4[(size_t)i * 2 + 1];
    uint4 r;
    r.x = pkh(v0.x, v0.y); r.y = pkh(v0.z, v0.w);
    r.z = pkh(v1.x, v1.y); r.w = pkh(v1.z, v1.w);
    ub16v[i] = r;
}

// ---------------------------------------------------------------------------
// k_qn: Qnh[i] = fp16(u2e[nodes[i]] @ W1b + b1) — only the 20k centers.
// Per-lane gathered fp32->fp16 A-fragments, B=w1b image (w1img nt 8..15).
// ---------------------------------------------------------------------------
__global__ __launch_bounds__(256) void k_qn(
    const int* __restrict__ nodes, const float* __restrict__ u2e,
    const uint4* __restrict__ w1img, const float* __restrict__ b1,
    unsigned short* __restrict__ Qnh, int n)
{
    const int t = threadIdx.x, w = t >> 6, l = t & 63;
    const int base = blockIdx.x * 128;

    half8 a[2][4];
    #pragma unroll
    for (int nt = 0; nt < 2; ++nt) {
        int row = min(base + w * 32 + nt * 16 + (l & 15), n - 1);
        int user = nodes[row];
        const float* rp = u2e + (size_t)user * DD + ((l >> 4) << 3);
        #pragma unroll
        for (int k4 = 0; k4 < 4; ++k4) {
            float4 v0 = *reinterpret_cast<const float4*>(rp + k4 * 32);
            float4 v1 = *reinterpret_cast<const float4*>(rp + k4 * 32 + 4);
            uint4 r;
            r.x = pkh(v0.x, v0.y); r.y = pkh(v0.z, v0.w);
            r.z = pkh(v1.x, v1.y); r.w = pkh(v1.z, v1.w);
            a[nt][k4] = __builtin_bit_cast(half8, r);
        }
    }
    const int chq = (l >> 4) << 2;
    #pragma unroll
    for (int mt = 0; mt < 8; ++mt) {
        half8 wf[4];
        #pragma unroll
        for (int k4 = 0; k4 < 4; ++k4)
            wf[k4] = __builtin_bit_cast(half8, w1img[((8 + mt) * 4 + k4) * 64 + l]);
        float4 b1v = *reinterpret_cast<const float4*>(&b1[mt * 16 + chq]);
        #pragma unroll
        for (int nt = 0; nt < 2; ++nt) {
            f32x4 acc = {0.f, 0.f, 0.f, 0.f};
            #pragma unroll
            for (int k4 = 0; k4 < 4; ++k4)
                acc = __builtin_amdgcn_mfma_f32_16x16x32_f16(wf[k4], a[nt][k4], acc, 0, 0, 0);
            int row = base + w * 32 + nt * 16 + (l & 15);
            if (row < n) {
                uint2 pk;
                pk.x = pkh(acc[0] + b1v.x, acc[1] + b1v.y);
                pk.y = pkh(acc[2] + b1v.z, acc[3] + b1v.w);
                *reinterpret_cast<uint2*>(&Qnh[(size_t)row * DD + mt * 16 + chq]) = pk;
            }
        }
    }
}

// ---------------------------------------------------------------------------
// k_node: 8 nodes/block (512 thr), 1 node/wave. ONE 256B gather per edge.
//  GEMM1: P = mfma(w1a, ub16[nb])  (D: row=ch 16mt+4g+r, col=edge c)
//  epilogue: relu(P + Qn) -> fp16 pairs hp[mt]
//  relayout hp (D-layout) -> hb (B-frag layout) via 64 shfl + 32 sel
//  GEMM2: h2pre = mfma(w2t, hb); logit fold; in-wave softmax;
//  tail: reuse ub16 regs, 16-lane butterfly, c==0 lanes store.
// Weight images staged once into LDS (linear, conflict-free ds_read_b128).
// ---------------------------------------------------------------------------
__global__ __launch_bounds__(512, 4) void k_node(
    const int* __restrict__ neigh, const _Float16* __restrict__ ub16,
    const unsigned short* __restrict__ Qnh, const uint4* __restrict__ w1img,
    const uint4* __restrict__ w2t, const float* __restrict__ b2,
    const float* __restrict__ w3, float4* __restrict__ out4, int n)
{
    __shared__ uint4 s_img[4096];     // [0..2047]=w1a frags, [2048..4095]=w2t

    const int t = threadIdx.x, w = t >> 6, l = t & 63;
    const int node = min(blockIdx.x * 8 + w, n - 1);
    const int g = l >> 4, c = l & 15;

    // ---- stage weight images (once per block)
    #pragma unroll
    for (int i = 0; i < 4; ++i) s_img[i * 512 + t] = w1img[i * 512 + t];
    #pragma unroll
    for (int i = 0; i < 4; ++i) s_img[2048 + i * 512 + t] = w2t[i * 512 + t];

    // ---- indices + the one gather stream + Qn prefetch
    const int idx0 = neigh[node * DEG + c];
    const int idx1 = neigh[node * DEG + 16 + c];
    const int koff = g * 8;
    half8 ub0[4], ub1[4];
    #pragma unroll
    for (int k4 = 0; k4 < 4; ++k4)
        ub0[k4] = *reinterpret_cast<const half8*>(&ub16[(size_t)idx0 * DD + k4 * 32 + koff]);
    #pragma unroll
    for (int k4 = 0; k4 < 4; ++k4)
        ub1[k4] = *reinterpret_cast<const half8*>(&ub16[(size_t)idx1 * DD + k4 * 32 + koff]);
    uint2 qnh[8];
    #pragma unroll
    for (int mt = 0; mt < 8; ++mt)
        qnh[mt] = *reinterpret_cast<const uint2*>(&Qnh[(size_t)node * DD + mt * 16 + g * 4]);

    __syncthreads();

    // ---- GEMM1 + fused epilogue: hp[mt] = fp16 pairs of relu(P+Q)
    uint2 hp0[8], hp1[8];
    #pragma unroll
    for (int mt = 0; mt < 8; ++mt) {
        half8 wf[4];
        #pragma unroll
        for (int k4 = 0; k4 < 4; ++k4)
            wf[k4] = __builtin_bit_cast(half8, s_img[(mt * 4 + k4) * 64 + l]);
        f32x4 a0 = {0.f, 0.f, 0.f, 0.f}, a1 = {0.f, 0.f, 0.f, 0.f};
        #pragma unroll
        for (int k4 = 0; k4 < 4; ++k4)
            a0 = __builtin_amdgcn_mfma_f32_16x16x32_f16(wf[k4], ub0[k4], a0, 0, 0, 0);
        #pragma unroll
        for (int k4 = 0; k4 < 4; ++k4)
            a1 = __builtin_amdgcn_mfma_f32_16x16x32_f16(wf[k4], ub1[k4], a1, 0, 0, 0);
        float q0 = h2f_lo(qnh[mt].x), q1 = h2f_hi(qnh[mt].x);
        float q2 = h2f_lo(qnh[mt].y), q3 = h2f_hi(qnh[mt].y);
        hp0[mt].x = pkh(fmaxf(a0[0] + q0, 0.f), fmaxf(a0[1] + q1, 0.f));
        hp0[mt].y = pkh(fmaxf(a0[2] + q2, 0.f), fmaxf(a0[3] + q3, 0.f));
        hp1[mt].x = pkh(fmaxf(a1[0] + q0, 0.f), fmaxf(a1[1] + q1, 0.f));
        hp1[mt].y = pkh(fmaxf(a1[2] + q2, 0.f), fmaxf(a1[3] + q3, 0.f));
    }

    // ---- relayout: D-layout (ch=16mt'+4g'+r, edge=c) -> B-frag
    //      (edge=c, k=32k4+8g+i). src lane g' = 2(g&1)+(j>>1), same c;
    //      mt' = 2k4+(g>>1); dword sel = j&1.
    const int srcA = ((g & 1) << 5) + c;
    const int hiSel = g >> 1;
    half8 hb0[4], hb1[4];
    #pragma unroll
    for (int k4 = 0; k4 < 4; ++k4) {
        unsigned d[4], e[4];
        #pragma unroll
        for (int j = 0; j < 4; ++j) {
            int src = srcA + ((j >> 1) << 4);
            unsigned vE = (unsigned)__shfl((int)((j & 1) ? hp0[2 * k4].y : hp0[2 * k4].x), src);
            unsigned vO = (unsigned)__shfl((int)((j & 1) ? hp0[2 * k4 + 1].y : hp0[2 * k4 + 1].x), src);
            d[j] = hiSel ? vO : vE;
            unsigned uE = (unsigned)__shfl((int)((j & 1) ? hp1[2 * k4].y : hp1[2 * k4].x), src);
            unsigned uO = (unsigned)__shfl((int)((j & 1) ? hp1[2 * k4 + 1].y : hp1[2 * k4 + 1].x), src);
            e[j] = hiSel ? uO : uE;
        }
        uint4 du = {d[0], d[1], d[2], d[3]};
        uint4 eu = {e[0], e[1], e[2], e[3]};
        hb0[k4] = __builtin_bit_cast(half8, du);
        hb1[k4] = __builtin_bit_cast(half8, eu);
    }

    // ---- GEMM2 + logit fold
    float pl0 = 0.f, pl1 = 0.f;
    #pragma unroll
    for (int mt = 0; mt < 8; ++mt) {
        half8 wf[4];
        #pragma unroll
        for (int k4 = 0; k4 < 4; ++k4)
            wf[k4] = __builtin_bit_cast(half8, s_img[2048 + (mt * 4 + k4) * 64 + l]);
        float4 b2v = *reinterpret_cast<const float4*>(&b2[mt * 16 + g * 4]);
        float4 w3v = *reinterpret_cast<const float4*>(&w3[mt * 16 + g * 4]);
        f32x4 a0 = {0.f, 0.f, 0.f, 0.f}, a1 = {0.f, 0.f, 0.f, 0.f};
        #pragma unroll
        for (int k4 = 0; k4 < 4; ++k4)
            a0 = __builtin_amdgcn_mfma_f32_16x16x32_f16(wf[k4], hb0[k4], a0, 0, 0, 0);
        #pragma unroll
        for (int k4 = 0; k4 < 4; ++k4)
            a1 = __builtin_amdgcn_mfma_f32_16x16x32_f16(wf[k4], hb1[k4], a1, 0, 0, 0);
        pl0 += fmaxf(a0[0] + b2v.x, 0.f) * w3v.x + fmaxf(a0[1] + b2v.y, 0.f) * w3v.y
             + fmaxf(a0[2] + b2v.z, 0.f) * w3v.z + fmaxf(a0[3] + b2v.w, 0.f) * w3v.w;
        pl1 += fmaxf(a1[0] + b2v.x, 0.f) * w3v.x + fmaxf(a1[1] + b2v.y, 0.f) * w3v.y
             + fmaxf(a1[2] + b2v.z, 0.f) * w3v.z + fmaxf(a1[3] + b2v.w, 0.f) * w3v.w;
    }
    pl0 += __shfl_xor(pl0, 16); pl0 += __shfl_xor(pl0, 32);
    pl1 += __shfl_xor(pl1, 16); pl1 += __shfl_xor(pl1, 32);

    // ---- in-wave softmax over the 32 edges
    float mx = fmaxf(pl0, pl1);
    #pragma unroll
    for (int mask = 1; mask <= 8; mask <<= 1) mx = fmaxf(mx, __shfl_xor(mx, mask));
    float e0 = __expf(pl0 - mx), e1 = __expf(pl1 - mx);
    float sm = e0 + e1;
    #pragma unroll
    for (int mask = 1; mask <= 8; mask <<= 1) sm += __shfl_xor(sm, mask);
    float inv = __frcp_rn(sm);
    float att0 = e0 * inv, att1 = e1 * inv;      // att for edges c and 16+c

    // ---- weighted sum reusing the SAME gathered registers (exact fp32)
    float o[4][8];
    #pragma unroll
    for (int k4 = 0; k4 < 4; ++k4)
        #pragma unroll
        for (int i = 0; i < 8; ++i)
            o[k4][i] = att0 * (float)ub0[k4][i] + att1 * (float)ub1[k4][i];
    #pragma unroll
    for (int mask = 1; mask <= 8; mask <<= 1) {
        #pragma unroll
        for (int k4 = 0; k4 < 4; ++k4)
            #pragma unroll
            for (int i = 0; i < 8; ++i)
                o[k4][i] += __shfl_xor(o[k4][i], mask);
    }
    if (c == 0) {   // lanes (g,0): store ch = 32*k4 + 8*g + {0..7}
        #pragma unroll
        for (int k4 = 0; k4 < 4; ++k4) {
            float4 r0 = make_float4(o[k4][0], o[k4][1], o[k4][2], o[k4][3]);
            float4 r1 = make_float4(o[k4][4], o[k4][5], o[k4][6], o[k4][7]);
            out4[(size_t)node * 32 + k4 * 8 + g * 2]     = r0;
            out4[(size_t)node * 32 + k4 * 8 + g * 2 + 1] = r1;
        }
    }
}

// ---------------------------------------------------------------------------
extern "C" void kernel_launch(void* const* d_in, const int* in_sizes, int n_in,
                              void* d_out, int out_size, void* d_ws, size_t ws_size,
                              hipStream_t stream)
{
    const int*   nodes = (const int*)  d_in[0];
    const int*   neigh = (const int*)  d_in[1];
    const float* u2e   = (const float*)d_in[3];
    const float* W1    = (const float*)d_in[4];
    const float* b1    = (const float*)d_in[5];
    const float* W2    = (const float*)d_in[6];
    const float* b2    = (const float*)d_in[7];
    const float* w3    = (const float*)d_in[8];
    // d_in[9] b3: cancels in segment softmax

    const int n = in_sizes[0];            // 20000
    const int U = in_sizes[3] / DD;       // 100000

    uint4*          w1img = (uint4*)d_ws;                    // 64 KB
    uint4*          w2t   = w1img + 4096;                    // 32 KB
    _Float16*       ub16  = (_Float16*)(w2t + 2048);         // 25.6 MB
    unsigned short* Qnh   = (unsigned short*)(ub16 + (size_t)U * DD); // 5.12 MB

    const int total8 = U * (DD / 8);      // 1.6M half8 chunks

    k_prep<<<24, 256, 0, stream>>>(W1, W2, w1img, w2t);
    k_cast<<<(total8 + 255) / 256, 256, 0, stream>>>(
        (const float4*)u2e, (uint4*)ub16, total8);
    k_qn<<<(n + 127) / 128, 256, 0, stream>>>(nodes, u2e, w1img, b1, Qnh, n);
    k_node<<<(n + 7) / 8, 512, 0, stream>>>(neigh, ub16, Qnh, w1img, w2t,
                                            b2, w3, (float4*)d_out, n);
}